// Round 8
// baseline (1092.344 us; speedup 1.0000x reference)
//
#include <hip/hip_runtime.h>

typedef __attribute__((ext_vector_type(8))) short bf16x8;
typedef __attribute__((ext_vector_type(4))) float f32x4;
typedef unsigned short ushort_t;

// ---------------------------------------------------------------------------
// fp32 -> bf16 RNE helpers
// ---------------------------------------------------------------------------
__device__ inline unsigned f2bf_rnd(float f) {
    unsigned u = __float_as_uint(f);
    return u + 0x7FFFu + ((u >> 16) & 1u);   // high 16 bits = RNE bf16
}

__device__ inline void split8(f32x4 a, f32x4 b, bf16x8& hv, bf16x8& lv) {
    float f[8] = {a.x, a.y, a.z, a.w, b.x, b.y, b.z, b.w};
    unsigned r[8], l[8];
#pragma unroll
    for (int j = 0; j < 8; ++j) r[j] = f2bf_rnd(f[j]);
#pragma unroll
    for (int j = 0; j < 8; ++j) {
        float hf = __uint_as_float(r[j] & 0xFFFF0000u);
        l[j] = f2bf_rnd(f[j] - hf);
    }
    union { unsigned u[4]; bf16x8 v; } H, L;
#pragma unroll
    for (int p = 0; p < 4; ++p) {
        H.u[p] = __builtin_amdgcn_perm(r[2 * p + 1], r[2 * p], 0x07060302u);
        L.u[p] = __builtin_amdgcn_perm(l[2 * p + 1], l[2 * p], 0x07060302u);
    }
    hv = H.v; lv = L.v;
}

// ---------------------------------------------------------------------------
// Kernel 1: pack W_in [64][1024] fp32 -> Wp bf16 hi/lo in MFMA-fragment layout
// Wp layout: [chunk 32][hl 2][kg 4][n 64][j 8]  (ushort), 256 KB total
// (byte-identical to R4)
// ---------------------------------------------------------------------------
__global__ void pack_w_kernel(const float* __restrict__ Win, ushort_t* __restrict__ Wp) {
    int idx = blockIdx.x * 256 + threadIdx.x;   // 0..65535
    int j  = idx & 7;
    int n  = (idx >> 3) & 63;
    int kg = (idx >> 9) & 3;
    int ch = idx >> 11;                          // 0..31
    int k  = ch * 32 + kg * 8 + j;
    float v = Win[n * 1024 + k];
    unsigned hb = f2bf_rnd(v) >> 16;
    float hf = __uint_as_float(hb << 16);
    unsigned lb = f2bf_rnd(v - hf) >> 16;
    Wp[((ch * 2 + 0) * 4 + kg) * 512 + n * 8 + j] = (ushort_t)hb;
    Wp[((ch * 2 + 1) * 4 + kg) * 512 + n * 8 + j] = (ushort_t)lb;
}

// ---------------------------------------------------------------------------
// Kernel 2: ATTRIBUTION PROBE — R4's GEMM body repeated 5x inside one
// dispatch (idempotent: every rep recomputes and rewrites the same ext).
// Forces this dispatch above the ~315us harness fills so it appears in the
// rocprof top-5 WITH counters.  True single-GEMM time = dur_us / 5.
// ---------------------------------------------------------------------------
__global__ __launch_bounds__(256) void gemm_ext_kernel(const float* __restrict__ x,
                                                       const ushort_t* __restrict__ Wp,
                                                       const float* __restrict__ bin,
                                                       float* __restrict__ ext) {
    const int tid  = threadIdx.x;
    const int lane = tid & 63;
    const int wave = tid >> 6;
    const int l15  = lane & 15;
    const int lg   = lane >> 4;          // k-group 0..3

    const long rowbase = (long)blockIdx.x * 64 + wave * 16;
    const float* xrow = x + (rowbase + l15) * 1024 + lg * 8;
    const ushort_t* bbase = Wp + lg * 512 + l15 * 8;

#pragma unroll 1
    for (int rep = 0; rep < 5; ++rep) {
        f32x4 acc[4];
#pragma unroll
        for (int n = 0; n < 4; ++n) acc[n] = (f32x4){0.f, 0.f, 0.f, 0.f};

        f32x4 As0[2][2], As1[2][2];   // [c][half]: col = i*64 + c*32 + half*4 + lg*8
        // prologue: As0 <- iter 0, As1 <- iter 1
#pragma unroll
        for (int c = 0; c < 2; ++c)
#pragma unroll
            for (int h = 0; h < 2; ++h) {
                As0[c][h] = __builtin_nontemporal_load((const f32x4*)(xrow + c * 32 + h * 4));
                As1[c][h] = __builtin_nontemporal_load((const f32x4*)(xrow + 64 + c * 32 + h * 4));
            }

        auto body = [&](int i, f32x4 (&cur)[2][2]) {
            // 1. issue B loads for this iter
            const ushort_t* bp = bbase + (long)i * 8192;
            bf16x8 B[2][4][2];
#pragma unroll
            for (int kc = 0; kc < 2; ++kc)
#pragma unroll
                for (int nq = 0; nq < 4; ++nq) {
                    B[kc][nq][0] = *(const bf16x8*)(bp + kc * 4096 + nq * 128);
                    B[kc][nq][1] = *(const bf16x8*)(bp + kc * 4096 + 2048 + nq * 128);
                }
            // 2. convert current A
            bf16x8 Ahi[2], Alo[2];
            split8(cur[0][0], cur[0][1], Ahi[0], Alo[0]);
            split8(cur[1][0], cur[1][1], Ahi[1], Alo[1]);
            // 3. refill this slot for iter i+2
            if (i + 2 < 16) {
                const float* xs = xrow + (i + 2) * 64;
#pragma unroll
                for (int c = 0; c < 2; ++c)
#pragma unroll
                    for (int h = 0; h < 2; ++h)
                        cur[c][h] = __builtin_nontemporal_load((const f32x4*)(xs + c * 32 + h * 4));
            }
            // 4. MFMAs
#pragma unroll
            for (int kc = 0; kc < 2; ++kc)
#pragma unroll
                for (int nq = 0; nq < 4; ++nq) {
                    acc[nq] = __builtin_amdgcn_mfma_f32_16x16x32_bf16(Ahi[kc], B[kc][nq][0], acc[nq], 0, 0, 0);
                    acc[nq] = __builtin_amdgcn_mfma_f32_16x16x32_bf16(Ahi[kc], B[kc][nq][1], acc[nq], 0, 0, 0);
                    acc[nq] = __builtin_amdgcn_mfma_f32_16x16x32_bf16(Alo[kc], B[kc][nq][0], acc[nq], 0, 0, 0);
                }
        };

#pragma unroll 1
        for (int ii = 0; ii < 16; ii += 2) {
            body(ii,     As0);
            body(ii + 1, As1);
        }

        // epilogue: add bias, store.
#pragma unroll
        for (int nq = 0; nq < 4; ++nq) {
            float bias = bin[nq * 16 + l15];
            long r0 = rowbase + lg * 4;
#pragma unroll
            for (int r = 0; r < 4; ++r) {
                ext[(r0 + r) * 64 + nq * 16 + l15] = acc[nq][r] + bias;
            }
        }
    }
}

// ---------------------------------------------------------------------------
// Kernel 3: recurrent scan.  (byte-identical to R4/R5/R6/R7)
// ---------------------------------------------------------------------------
__global__ __launch_bounds__(64) void scan_kernel(const float* __restrict__ ext,
                                                  const float* __restrict__ Wrec,
                                                  const float* __restrict__ brec,
                                                  float* __restrict__ states) {
    const int b = blockIdx.x;
    const int h = threadIdx.x;   // 0..63

    float w[64];
#pragma unroll
    for (int i = 0; i < 16; ++i)
        *(float4*)&w[i * 4] = *(const float4*)&Wrec[h * 64 + i * 4];
    const float bias = brec[h];

    __shared__ float in_lds[2][64];

    const float* ep = ext + (size_t)b * 512 * 64 + h;
    float* sp = states + (size_t)b * 512 * 64 + h;

    float s = 0.f;
    float e0 = ep[0];
    float e1 = ep[64];

    for (int t = 0; t < 512; ++t) {
        float in = s + e0;
        in_lds[t & 1][h] = in;
        e0 = e1;
        if (t + 2 < 512) e1 = ep[(size_t)(t + 2) * 64];
        // single-wave block: writes visible after lgkmcnt(0); no barrier, no vmcnt drain
        asm volatile("s_waitcnt lgkmcnt(0)" ::: "memory");

        float a0 = bias, a1 = 0.f, a2 = 0.f, a3 = 0.f;
#pragma unroll
        for (int i = 0; i < 16; ++i) {
            float4 v = *(const float4*)&in_lds[t & 1][i * 4];
            a0 += v.x * w[i * 4 + 0];
            a1 += v.y * w[i * 4 + 1];
            a2 += v.z * w[i * 4 + 2];
            a3 += v.w * w[i * 4 + 3];
        }
        s = fmaxf((a0 + a1) + (a2 + a3), 0.f);
        sp[(size_t)t * 64] = s;
    }
}

// ---------------------------------------------------------------------------
// Kernel 4: output head.  (byte-identical to R4/R5/R6/R7)
// ---------------------------------------------------------------------------
__global__ __launch_bounds__(256) void head_kernel(const float* __restrict__ states,
                                                   const float* __restrict__ Wo1,
                                                   const float* __restrict__ bo1,
                                                   const float* __restrict__ Wo2,
                                                   const float* __restrict__ bo2,
                                                   float* __restrict__ out) {
    __shared__ float W1t[64][32];   // W1t[k][j] = Wo1[j][k]
    __shared__ float w2s[64];
    __shared__ float b1s[32];
    __shared__ float b2s[2];

    const int tid = threadIdx.x;
    for (int idx = tid; idx < 2048; idx += 256) {
        int j = idx >> 6, k = idx & 63;
        W1t[k][j] = Wo1[idx];
    }
    if (tid < 64) w2s[tid] = Wo2[tid];
    if (tid < 32) b1s[tid] = bo1[tid];
    if (tid < 2)  b2s[tid] = bo2[tid];
    __syncthreads();

    const size_t row = (size_t)blockIdx.x * 256 + tid;  // 0..131071
    const float* srow = states + row * 64;

    float st[64];
#pragma unroll
    for (int i = 0; i < 16; ++i)
        *(float4*)&st[i * 4] = *(const float4*)&srow[i * 4];

    float4 hacc[8];
#pragma unroll
    for (int j4 = 0; j4 < 8; ++j4) hacc[j4] = (float4){0.f, 0.f, 0.f, 0.f};

#pragma unroll
    for (int k = 0; k < 64; ++k) {
        float sk = st[k];
#pragma unroll
        for (int j4 = 0; j4 < 8; ++j4) {
            float4 wv = *(const float4*)&W1t[k][j4 * 4];
            hacc[j4].x += sk * wv.x;
            hacc[j4].y += sk * wv.y;
            hacc[j4].z += sk * wv.z;
            hacc[j4].w += sk * wv.w;
        }
    }

    float o0 = b2s[0], o1 = b2s[1];
#pragma unroll
    for (int j4 = 0; j4 < 8; ++j4) {
        float4 bv = *(const float4*)&b1s[j4 * 4];
        float hj[4] = {fmaxf(hacc[j4].x + bv.x, 0.f), fmaxf(hacc[j4].y + bv.y, 0.f),
                       fmaxf(hacc[j4].z + bv.z, 0.f), fmaxf(hacc[j4].w + bv.w, 0.f)};
#pragma unroll
        for (int r = 0; r < 4; ++r) {
            int j = j4 * 4 + r;
            o0 += hj[r] * w2s[j];
            o1 += hj[r] * w2s[32 + j];
        }
    }
    float2 ov = {o0, o1};
    *(float2*)&out[row * 2] = ov;
}

// ---------------------------------------------------------------------------
extern "C" void kernel_launch(void* const* d_in, const int* in_sizes, int n_in,
                              void* d_out, int out_size, void* d_ws, size_t ws_size,
                              hipStream_t stream) {
    (void)in_sizes; (void)n_in; (void)out_size; (void)ws_size;

    const float* x     = (const float*)d_in[0];
    const float* W_in  = (const float*)d_in[1];
    const float* b_in  = (const float*)d_in[2];
    const float* W_rec = (const float*)d_in[3];
    const float* b_rec = (const float*)d_in[4];
    const float* W_o1  = (const float*)d_in[5];
    const float* b_o1  = (const float*)d_in[6];
    const float* W_o2  = (const float*)d_in[7];
    const float* b_o2  = (const float*)d_in[8];
    float* out = (float*)d_out;

    char* ws = (char*)d_ws;
    ushort_t* Wp   = (ushort_t*)ws;                                  // 256 KB
    float* ext     = (float*)(ws + (1u << 20));                      // 32 MB
    float* states  = (float*)(ws + (1u << 20) + (32u << 20));        // 32 MB

    pack_w_kernel<<<256, 256, 0, stream>>>(W_in, Wp);
    gemm_ext_kernel<<<2048, 256, 0, stream>>>(x, Wp, b_in, ext);   // 5x internal reps (probe)
    scan_kernel<<<256, 64, 0, stream>>>(ext, W_rec, b_rec, states);
    head_kernel<<<512, 256, 0, stream>>>(states, W_o1, b_o1, W_o2, b_o2, out);
}

// Round 10
// 359.322 us; speedup vs baseline: 3.0400x; 3.0400x over previous
//
#include <hip/hip_runtime.h>

typedef __attribute__((ext_vector_type(8))) short bf16x8;
typedef __attribute__((ext_vector_type(4))) float f32x4;
typedef unsigned short ushort_t;

// ---------------------------------------------------------------------------
// fp32 -> bf16 RNE helpers
// ---------------------------------------------------------------------------
__device__ inline unsigned f2bf_rnd(float f) {
    unsigned u = __float_as_uint(f);
    return u + 0x7FFFu + ((u >> 16) & 1u);   // high 16 bits = RNE bf16
}

__device__ inline void split8(f32x4 a, f32x4 b, bf16x8& hv, bf16x8& lv) {
    float f[8] = {a.x, a.y, a.z, a.w, b.x, b.y, b.z, b.w};
    unsigned r[8], l[8];
#pragma unroll
    for (int j = 0; j < 8; ++j) r[j] = f2bf_rnd(f[j]);
#pragma unroll
    for (int j = 0; j < 8; ++j) {
        float hf = __uint_as_float(r[j] & 0xFFFF0000u);
        l[j] = f2bf_rnd(f[j] - hf);
    }
    union { unsigned u[4]; bf16x8 v; } H, L;
#pragma unroll
    for (int p = 0; p < 4; ++p) {
        H.u[p] = __builtin_amdgcn_perm(r[2 * p + 1], r[2 * p], 0x07060302u);
        L.u[p] = __builtin_amdgcn_perm(l[2 * p + 1], l[2 * p], 0x07060302u);
    }
    hv = H.v; lv = L.v;
}

// ---------------------------------------------------------------------------
// Kernel 1: pack W_in [64][1024] fp32 -> Wp bf16 hi/lo in MFMA-fragment layout
// Wp layout: [chunk 32][hl 2][kg 4][n 64][j 8]  (ushort), 256 KB total
// ---------------------------------------------------------------------------
__global__ void pack_w_kernel(const float* __restrict__ Win, ushort_t* __restrict__ Wp) {
    int idx = blockIdx.x * 256 + threadIdx.x;   // 0..65535
    int j  = idx & 7;
    int n  = (idx >> 3) & 63;
    int kg = (idx >> 9) & 3;
    int ch = idx >> 11;                          // 0..31
    int k  = ch * 32 + kg * 8 + j;
    float v = Win[n * 1024 + k];
    unsigned hb = f2bf_rnd(v) >> 16;
    float hf = __uint_as_float(hb << 16);
    unsigned lb = f2bf_rnd(v - hf) >> 16;
    Wp[((ch * 2 + 0) * 4 + kg) * 512 + n * 8 + j] = (ushort_t)hb;
    Wp[((ch * 2 + 1) * 4 + kg) * 512 + n * 8 + j] = (ushort_t)lb;
}

// ---------------------------------------------------------------------------
// Kernel 2 (v3b): ext = x @ W_in^T + b_in, bf16 MFMA 3-term split.
// BM=64, BK=64, 256 thr (4 waves x 16 rows).  Staged pipeline per tile:
//   write_tile(buf)  -> implicit vmcnt waits hit loads issued a FULL iter ago
//   lgkmcnt(0)+s_barrier (ONE per tile; vmcnt untouched -> prefetch in flight)
//   load_tile(kt+1)  -> regs, overlaps compute
//   compute(buf)
// B staged to LDS once per block per tile (FULL 16 KB: 4 x uint4 per thread
// -- R9's NaN was this at half size reading uninitialized LDS).
// LDS 64 KB -> 2 blocks/CU; alternating block phases keep HBM pipe fed.
// ---------------------------------------------------------------------------
__global__ __launch_bounds__(256) void gemm_ext_kernel(const float* __restrict__ x,
                                                       const ushort_t* __restrict__ Wp,
                                                       const float* __restrict__ bin,
                                                       float* __restrict__ ext) {
    __shared__ __align__(16) float    Asm[2][64 * 64];   // 2 x 16 KB
    __shared__ __align__(16) ushort_t Bsm[2][8192];      // 2 x 16 KB

    const int tid  = threadIdx.x;        // 0..255
    const int lane = tid & 63;
    const int wave = tid >> 6;
    const int l15  = lane & 15;
    const int lg   = lane >> 4;

    const long rowbase = (long)blockIdx.x * 64;

    int arow[4], aseg[4];
#pragma unroll
    for (int i = 0; i < 4; ++i) {
        int slot = i * 256 + tid;
        arow[i] = slot >> 4;     // 0..63
        aseg[i] = slot & 15;     // 16B segment within 64-float row chunk
    }

    f32x4 Ar[4];
    uint4 Br[4];

    auto load_tile = [&](int kt) {
        const float* xb = x + rowbase * 1024 + kt * 64;
#pragma unroll
        for (int i = 0; i < 4; ++i)
            Ar[i] = *(const f32x4*)(xb + (long)arow[i] * 1024 + aseg[i] * 4);
        const ushort_t* wb = Wp + kt * 8192;
#pragma unroll
        for (int i = 0; i < 4; ++i)
            Br[i] = *(const uint4*)(wb + (i * 256 + tid) * 8);
    };
    auto write_tile = [&](int buf) {
#pragma unroll
        for (int i = 0; i < 4; ++i)
            *(f32x4*)(&Asm[buf][arow[i] * 64 + aseg[i] * 4]) = Ar[i];
#pragma unroll
        for (int i = 0; i < 4; ++i)
            *(uint4*)(&Bsm[buf][(i * 256 + tid) * 8]) = Br[i];
    };

    f32x4 acc[4];
#pragma unroll
    for (int n = 0; n < 4; ++n) acc[n] = (f32x4){0.f, 0.f, 0.f, 0.f};

    load_tile(0);

#pragma unroll 1
    for (int kt = 0; kt < 16; ++kt) {
        const int buf = kt & 1;
        write_tile(buf);
        // own lgkm drained + exec barrier; vmcnt NOT drained.
        asm volatile("s_waitcnt lgkmcnt(0)\n\ts_barrier" ::: "memory");
        if (kt < 15) load_tile(kt + 1);

#pragma unroll
        for (int kc = 0; kc < 2; ++kc) {
            const float* ap = &Asm[buf][(wave * 16 + l15) * 64 + kc * 32 + lg * 8];
            f32x4 a0 = *(const f32x4*)ap;
            f32x4 a1 = *(const f32x4*)(ap + 4);
            bf16x8 Ahi, Alo;
            split8(a0, a1, Ahi, Alo);
            const ushort_t* bp = &Bsm[buf][kc * 4096 + lg * 512 + l15 * 8];
#pragma unroll
            for (int nq = 0; nq < 4; ++nq) {
                bf16x8 bh = *(const bf16x8*)(bp + nq * 128);
                bf16x8 bl = *(const bf16x8*)(bp + 2048 + nq * 128);
                acc[nq] = __builtin_amdgcn_mfma_f32_16x16x32_bf16(Ahi, bh, acc[nq], 0, 0, 0);
                acc[nq] = __builtin_amdgcn_mfma_f32_16x16x32_bf16(Ahi, bl, acc[nq], 0, 0, 0);
                acc[nq] = __builtin_amdgcn_mfma_f32_16x16x32_bf16(Alo, bh, acc[nq], 0, 0, 0);
            }
        }
    }

    // epilogue: add bias, store.  C/D map: col = lane&15, row = (lane>>4)*4 + r
#pragma unroll
    for (int nq = 0; nq < 4; ++nq) {
        float bias = bin[nq * 16 + l15];
        long r0 = rowbase + wave * 16 + lg * 4;
#pragma unroll
        for (int r = 0; r < 4; ++r) {
            ext[(r0 + r) * 64 + nq * 16 + l15] = acc[nq][r] + bias;
        }
    }
}

// ---------------------------------------------------------------------------
// Kernel 3 (v2): recurrent scan, NO LDS round-trip.
// Lane h holds W_rec[h][*] (64 VGPR) and s[h].  Broadcast of in[k] via
// compile-time v_readlane -> SGPR, consumed directly by v_fmac (1 SGPR
// operand allowed).  No barriers, no lgkm waits.  4-deep ext prefetch.
// ---------------------------------------------------------------------------
__device__ inline float rl(float v, int k) {
    return __int_as_float(__builtin_amdgcn_readlane(__float_as_int(v), k));
}

__global__ __launch_bounds__(64) void scan_kernel(const float* __restrict__ ext,
                                                  const float* __restrict__ Wrec,
                                                  const float* __restrict__ brec,
                                                  float* __restrict__ states) {
    const int b = blockIdx.x;
    const int h = threadIdx.x;   // 0..63

    float w[64];
#pragma unroll
    for (int i = 0; i < 16; ++i)
        *(f32x4*)&w[i * 4] = *(const f32x4*)&Wrec[h * 64 + i * 4];
    const float bias = brec[h];

    const float* ep = ext + (size_t)b * 512 * 64 + h;
    float* sp = states + (size_t)b * 512 * 64 + h;

    float s = 0.f;
    float e0 = ep[0];
    float e1 = ep[64];
    float e2 = ep[128];
    float e3 = ep[192];

#define SCAN_STEP(EREG, IDX)                                                   \
    {                                                                          \
        float in = s + EREG;                                                   \
        int tn = t + 4 + (IDX); tn = tn > 511 ? 511 : tn;                      \
        EREG = ep[(size_t)tn * 64];                                            \
        float a0 = bias, a1 = 0.f, a2 = 0.f, a3 = 0.f;                         \
        _Pragma("unroll")                                                      \
        for (int k = 0; k < 64; k += 4) {                                      \
            a0 = fmaf(w[k + 0], rl(in, k + 0), a0);                            \
            a1 = fmaf(w[k + 1], rl(in, k + 1), a1);                            \
            a2 = fmaf(w[k + 2], rl(in, k + 2), a2);                            \
            a3 = fmaf(w[k + 3], rl(in, k + 3), a3);                            \
        }                                                                      \
        s = fmaxf((a0 + a1) + (a2 + a3), 0.f);                                 \
        sp[(size_t)(t + (IDX)) * 64] = s;                                      \
    }

#pragma unroll 1
    for (int t = 0; t < 512; t += 4) {
        SCAN_STEP(e0, 0)
        SCAN_STEP(e1, 1)
        SCAN_STEP(e2, 2)
        SCAN_STEP(e3, 3)
    }
#undef SCAN_STEP
}

// ---------------------------------------------------------------------------
// Kernel 4: output head.  (byte-identical to R4..R9)
// ---------------------------------------------------------------------------
__global__ __launch_bounds__(256) void head_kernel(const float* __restrict__ states,
                                                   const float* __restrict__ Wo1,
                                                   const float* __restrict__ bo1,
                                                   const float* __restrict__ Wo2,
                                                   const float* __restrict__ bo2,
                                                   float* __restrict__ out) {
    __shared__ float W1t[64][32];   // W1t[k][j] = Wo1[j][k]
    __shared__ float w2s[64];
    __shared__ float b1s[32];
    __shared__ float b2s[2];

    const int tid = threadIdx.x;
    for (int idx = tid; idx < 2048; idx += 256) {
        int j = idx >> 6, k = idx & 63;
        W1t[k][j] = Wo1[idx];
    }
    if (tid < 64) w2s[tid] = Wo2[tid];
    if (tid < 32) b1s[tid] = bo1[tid];
    if (tid < 2)  b2s[tid] = bo2[tid];
    __syncthreads();

    const size_t row = (size_t)blockIdx.x * 256 + tid;  // 0..131071
    const float* srow = states + row * 64;

    float st[64];
#pragma unroll
    for (int i = 0; i < 16; ++i)
        *(float4*)&st[i * 4] = *(const float4*)&srow[i * 4];

    float4 hacc[8];
#pragma unroll
    for (int j4 = 0; j4 < 8; ++j4) hacc[j4] = (float4){0.f, 0.f, 0.f, 0.f};

#pragma unroll
    for (int k = 0; k < 64; ++k) {
        float sk = st[k];
#pragma unroll
        for (int j4 = 0; j4 < 8; ++j4) {
            float4 wv = *(const float4*)&W1t[k][j4 * 4];
            hacc[j4].x += sk * wv.x;
            hacc[j4].y += sk * wv.y;
            hacc[j4].z += sk * wv.z;
            hacc[j4].w += sk * wv.w;
        }
    }

    float o0 = b2s[0], o1 = b2s[1];
#pragma unroll
    for (int j4 = 0; j4 < 8; ++j4) {
        float4 bv = *(const float4*)&b1s[j4 * 4];
        float hj[4] = {fmaxf(hacc[j4].x + bv.x, 0.f), fmaxf(hacc[j4].y + bv.y, 0.f),
                       fmaxf(hacc[j4].z + bv.z, 0.f), fmaxf(hacc[j4].w + bv.w, 0.f)};
#pragma unroll
        for (int r = 0; r < 4; ++r) {
            int j = j4 * 4 + r;
            o0 += hj[r] * w2s[j];
            o1 += hj[r] * w2s[32 + j];
        }
    }
    float2 ov = {o0, o1};
    *(float2*)&out[row * 2] = ov;
}

// ---------------------------------------------------------------------------
extern "C" void kernel_launch(void* const* d_in, const int* in_sizes, int n_in,
                              void* d_out, int out_size, void* d_ws, size_t ws_size,
                              hipStream_t stream) {
    (void)in_sizes; (void)n_in; (void)out_size; (void)ws_size;

    const float* x     = (const float*)d_in[0];
    const float* W_in  = (const float*)d_in[1];
    const float* b_in  = (const float*)d_in[2];
    const float* W_rec = (const float*)d_in[3];
    const float* b_rec = (const float*)d_in[4];
    const float* W_o1  = (const float*)d_in[5];
    const float* b_o1  = (const float*)d_in[6];
    const float* W_o2  = (const float*)d_in[7];
    const float* b_o2  = (const float*)d_in[8];
    float* out = (float*)d_out;

    char* ws = (char*)d_ws;
    ushort_t* Wp   = (ushort_t*)ws;                                  // 256 KB
    float* ext     = (float*)(ws + (1u << 20));                      // 32 MB
    float* states  = (float*)(ws + (1u << 20) + (32u << 20));        // 32 MB

    pack_w_kernel<<<256, 256, 0, stream>>>(W_in, Wp);
    gemm_ext_kernel<<<2048, 256, 0, stream>>>(x, Wp, b_in, ext);
    scan_kernel<<<256, 64, 0, stream>>>(ext, W_rec, b_rec, states);
    head_kernel<<<512, 256, 0, stream>>>(states, W_o1, b_o1, W_o2, b_o2, out);
}